// Round 19
// baseline (419.412 us; speedup 1.0000x reference)
//
#include <hip/hip_runtime.h>

#define M_DIM 16384
#define N_DIM 4096
#define K_DIM 4096
#define NCLUST 16

#define BM 256
#define BN 128
#define KB4 2048              // bytes per row (fp4: 4096 elements / 2)
#define TKB 64                // K-tile bytes per row (128 fp4 elements)
#define NT 32                 // K-tiles

typedef unsigned short u16;
typedef unsigned char u8;
typedef float floatx4 __attribute__((ext_vector_type(4)));
typedef int int4v __attribute__((ext_vector_type(4)));
typedef int int8v __attribute__((ext_vector_type(8)));

typedef const unsigned int __attribute__((address_space(1))) gu32;
typedef unsigned int __attribute__((address_space(3))) lu32;

// float -> fp4 e2m1 code (values pre-scaled to ~N(0,1)); grid {0,.5,1,1.5,2,3,4,6}
__device__ __forceinline__ unsigned f2fp4(float x) {
  unsigned s = (__float_as_uint(x) >> 28) & 0x8u;
  float ax = fabsf(x);
  unsigned m;
  if      (ax < 0.25f) m = 0;
  else if (ax < 0.75f) m = 1;
  else if (ax < 1.25f) m = 2;
  else if (ax < 1.75f) m = 3;
  else if (ax < 2.5f)  m = 4;
  else if (ax < 3.5f)  m = 5;
  else if (ax < 5.0f)  m = 6;
  else                 m = 7;
  return s | m;
}

// ---------------- zero colsq only (s_part is fully written each call) ----------------
__global__ __launch_bounds__(256) void zero_kernel(float* __restrict__ p, int n) {
  int i = blockIdx.x * 256 + threadIdx.x;
  if (i < n) p[i] = 0.f;
}

// ---------------- z row-normalize -> fp4 (x64); out1 copy fused into GEMM ----------------
__global__ __launch_bounds__(256) void znorm_kernel(const float* __restrict__ z,
                                                    u8* __restrict__ zn) {
  const int row = blockIdx.x;
  const int t = threadIdx.x;
  const size_t base = (size_t)row * K_DIM;
  const float4* zr = (const float4*)(z + base);
  float4 v[4];                       // 16 contiguous elements: 16t .. 16t+15
  float ss = 0.f;
#pragma unroll
  for (int i = 0; i < 4; i++) {
    v[i] = zr[t * 4 + i];
    ss += v[i].x * v[i].x + v[i].y * v[i].y + v[i].z * v[i].z + v[i].w * v[i].w;
  }
#pragma unroll
  for (int m = 1; m <= 32; m <<= 1) ss += __shfl_xor(ss, m, 64);
  __shared__ float red[4];
  if ((t & 63) == 0) red[t >> 6] = ss;
  __syncthreads();
  float tot = red[0] + red[1] + red[2] + red[3];
  float sc = 64.0f / fmaxf(sqrtf(tot), 1e-8f);
  uint2* znr = (uint2*)(zn + (size_t)row * KB4);
  unsigned wlo = 0, whi = 0;
#pragma unroll
  for (int i = 0; i < 4; i++) {
    unsigned p = f2fp4(v[i].x * sc) | (f2fp4(v[i].y * sc) << 4) |
                 (f2fp4(v[i].z * sc) << 8) | (f2fp4(v[i].w * sc) << 12);
    if (i < 2) wlo |= p << (16 * i); else whi |= p << (16 * (i - 2));
  }
  uint2 pk; pk.x = wlo; pk.y = whi;
  znr[t] = pk;
}

// ---------------- D column squared-norms ----------------
__global__ __launch_bounds__(256) void colsq_kernel(const float* __restrict__ D,
                                                    float* __restrict__ colsq) {
  const int col = blockIdx.x * 256 + threadIdx.x;
  const int r0 = blockIdx.y * 128;
  float ss = 0.f;
#pragma unroll 4
  for (int r = 0; r < 128; r++) {
    float d = D[(size_t)(r0 + r) * N_DIM + col];
    ss += d * d;
  }
  atomicAdd(&colsq[col], ss);
}

// ---------------- D col-normalize + transpose -> fp4 (x64) DnT[N][K/2] ----------------
__global__ __launch_bounds__(256) void dnt_kernel(const float* __restrict__ D,
                                                  const float* __restrict__ colsq,
                                                  u8* __restrict__ dnt) {
  __shared__ float tile[64][65];
  const int c0 = blockIdx.x * 64, r0 = blockIdx.y * 64;
  const int t = threadIdx.x;
  const int tr = t >> 4;
  const int tc = (t & 15) * 4;
#pragma unroll
  for (int i = 0; i < 4; i++) {
    int row = i * 16 + tr;
    float4 v = *(const float4*)(D + (size_t)(r0 + row) * N_DIM + c0 + tc);
    tile[row][tc + 0] = v.x; tile[row][tc + 1] = v.y;
    tile[row][tc + 2] = v.z; tile[row][tc + 3] = v.w;
  }
  __syncthreads();
#pragma unroll
  for (int i = 0; i < 4; i++) {
    int nl = i * 16 + tr;
    float sc = 64.0f / fmaxf(sqrtf(colsq[c0 + nl]), 1e-8f);
    u16 pk = (u16)(f2fp4(tile[tc + 0][nl] * sc) | (f2fp4(tile[tc + 1][nl] * sc) << 4) |
                   (f2fp4(tile[tc + 2][nl] * sc) << 8) | (f2fp4(tile[tc + 3][nl] * sc) << 12));
    *(u16*)(dnt + (size_t)(c0 + nl) * KB4 + ((r0 + tc) >> 1)) = pk;
  }
}

// ---------------- GEMM: 256x128, fp4 e2m1, mfma_scale 16x16x128 fmt=4 ----------------
// R19 = R18 with the z->out1 copy interleaved INTO the K-loop with uniform
// vmcnt accounting: every main-loop ITER issues exactly 5 VMEM ops at the top
// {copyS float2(prev), copyL float2(next), 3 stage ops}, so the counted wait
// is VM5 everywhere — by construction it drains all prior-iteration ops
// (stage kt+1 AND older copy ops) before the fragment refills. (R15 failed
// because its copy made per-iter VMEM counts non-uniform.) 30 ITERs x 4 KB
// cover 120 KB of the block's 128 KB slice; chunks 30,31 finish in the tail
// after VM0. Fragments refilled in the MFMA shadow; non-atomic s_part output.
__global__ __launch_bounds__(512, 1) void gemm_kernel(const u8* __restrict__ zn,
                                                      const u8* __restrict__ dnt,
                                                      const float* __restrict__ zsrc,
                                                      float* __restrict__ out1,
                                                      float* __restrict__ s_part) {
  __shared__ u8 ldsA[3 * BM * TKB];   // 3 x 16 KB
  __shared__ u8 ldsB[3 * BN * TKB];   // 3 x 8 KB -> 72 KB total

  const int t = threadIdx.x;
  const int w = t >> 6, l = t & 63;
  const int lr = l & 15, lk = l >> 4;

  // XCD swizzle: 2048 blocks, 256 contiguous work-ids per XCD
  const int bid = blockIdx.x;
  const int swz = (bid & 7) * 256 + (bid >> 3);
  const int bx = swz & 31, by = swz >> 5;
  const int bm = by * BM, bn = bx * BN;
  const int wm = (w >> 1) * 64, wn = (w & 1) * 64;

  // ---- fused-copy pointers: block owns 32768 floats = 16384 float2 ----
  const float2* csrc2 = (const float2*)zsrc + (size_t)bid * 16384 + t;
  float2* cdst2 = (float2*)out1 + (size_t)bid * 16384 + t;
  float2 cbuf;

  // ---- staging: pre-swizzled per-lane sources, wave-uniform LDS dests ----
  const int sslot = (t & 3) ^ ((t >> 3) & 3);
  const u8* pA = zn + (size_t)(bm + (t >> 2)) * KB4 + sslot * 16;
  const u8* pB = dnt + (size_t)(bn + (t >> 2)) * KB4 + sslot * 16;

#define STAGE(OA, KT) do { \
    __builtin_amdgcn_global_load_lds((gu32*)(pA + (KT) * TKB), \
        (lu32*)&ldsA[(OA) + w * 1024], 16, 0, 0); \
    __builtin_amdgcn_global_load_lds((gu32*)(pA + (size_t)128 * KB4 + (KT) * TKB), \
        (lu32*)&ldsA[(OA) + 8192 + w * 1024], 16, 0, 0); \
    __builtin_amdgcn_global_load_lds((gu32*)(pB + (KT) * TKB), \
        (lu32*)&ldsB[((OA) >> 1) + w * 1024], 16, 0, 0); \
  } while (0)

  // ---- ds_read fragment byte offsets: slot = lk ^ ((row>>1)&3) ----
  int aOff[4], bOff[4];
#pragma unroll
  for (int m = 0; m < 4; m++) {
    int row = wm + m * 16 + lr;
    aOff[m] = row * TKB + ((lk ^ ((row >> 1) & 3)) * 16);
  }
#pragma unroll
  for (int n = 0; n < 4; n++) {
    int row = wn + n * 16 + lr;
    bOff[n] = row * TKB + ((lk ^ ((row >> 1) & 3)) * 16);
  }

  int8v af[4], bf[4];
  floatx4 acc[4][4] = {};

  // full-def refill: low half from LDS, high half zeroed (fp4 reads v[0:3])
#define LDFRAG(F, base, off) do { \
    int4v* _h = (int4v*)&(F); \
    _h[0] = *(const int4v*)((base) + (off)); \
    _h[1] = (int4v){0, 0, 0, 0}; \
  } while (0)

  // full-tile preload (prologue only)
#define READ_ALL(OA) do { \
    const u8* _ab = ldsA + (OA); \
    const u8* _bb = ldsB + ((OA) >> 1); \
    _Pragma("unroll") \
    for (int ni = 0; ni < 4; ni++) LDFRAG(bf[ni], _bb, bOff[ni]); \
    _Pragma("unroll") \
    for (int mi = 0; mi < 4; mi++) LDFRAG(af[mi], _ab, aOff[mi]); \
  } while (0)

#define MFMA_H(M0) do { \
    __builtin_amdgcn_s_setprio(1); \
    _Pragma("unroll") \
    for (int mi = 0; mi < 2; mi++) \
      _Pragma("unroll") \
      for (int ni = 0; ni < 4; ni++) \
        acc[(M0) + mi][ni] = __builtin_amdgcn_mfma_scale_f32_16x16x128_f8f6f4( \
            af[(M0) + mi], bf[ni], acc[(M0) + mi][ni], 4, 4, 0, 127u, 0, 127u); \
    __builtin_amdgcn_s_setprio(0); \
  } while (0)

#define VM5 asm volatile("s_waitcnt vmcnt(5)" ::: "memory")
#define VM3 asm volatile("s_waitcnt vmcnt(3)" ::: "memory")
#define VM0 asm volatile("s_waitcnt vmcnt(0)" ::: "memory")

  // main-loop K-tile: 5 VMEM ops at top {copyS, copyL, stage x3}; VM5 drains
  // all prior-iteration ops before refills. ON = next buf.
#define ITER_C(OC, ON, KT2) do { \
    __builtin_amdgcn_s_barrier(); \
    __builtin_amdgcn_sched_barrier(0); \
    cdst2[0] = cbuf; \
    cbuf = csrc2[512]; \
    csrc2 += 512; cdst2 += 512; \
    STAGE(KT2##_O, KT2); \
    MFMA_H(0); \
    VM5; \
    LDFRAG(af[0], ldsA + (ON), aOff[0]); \
    LDFRAG(af[1], ldsA + (ON), aOff[1]); \
    MFMA_H(2); \
    { \
      const u8* _bb = ldsB + ((ON) >> 1); \
      _Pragma("unroll") \
      for (int ni = 0; ni < 4; ni++) LDFRAG(bf[ni], _bb, bOff[ni]); \
      LDFRAG(af[2], ldsA + (ON), aOff[2]); \
      LDFRAG(af[3], ldsA + (ON), aOff[3]); \
    } \
  } while (0)

  // tail ITER (no stage, no copy)
#define ITER_T(ON, WT, RDNEXT) do { \
    __builtin_amdgcn_s_barrier(); \
    __builtin_amdgcn_sched_barrier(0); \
    MFMA_H(0); \
    WT; \
    if (RDNEXT) { \
      LDFRAG(af[0], ldsA + (ON), aOff[0]); \
      LDFRAG(af[1], ldsA + (ON), aOff[1]); \
    } \
    MFMA_H(2); \
    if (RDNEXT) { \
      const u8* _bb = ldsB + ((ON) >> 1); \
      _Pragma("unroll") \
      for (int ni = 0; ni < 4; ni++) LDFRAG(bf[ni], _bb, bOff[ni]); \
      LDFRAG(af[2], ldsA + (ON), aOff[2]); \
      LDFRAG(af[3], ldsA + (ON), aOff[3]); \
    } \
  } while (0)

#define O0 0
#define O1 16384
#define O2 32768

  // prologue: copyL chunk0; stage tiles 0,1; drain chunk0+tile0; preload frags
  cbuf = csrc2[0];
  STAGE(O0, 0); STAGE(O1, 1);
  VM3;
  __builtin_amdgcn_s_barrier();
  READ_ALL(O0);

  // 30 main ITERs (tiles 0..29), each staging kt+2 and copying one chunk
  for (int kt = 0; kt < NT - 2; kt += 3) {
#define kp2_O O2
#define kp3_O O0
#define kp4_O O1
    { const int kp2 = kt + 2; ITER_C(O0, O1, kp2); }
    { const int kp3 = kt + 3; ITER_C(O1, O2, kp3); }
    { const int kp4 = kt + 4; ITER_C(O2, O0, kp4); }
#undef kp2_O
#undef kp3_O
#undef kp4_O
  }
  // tile 30 (buf0): drain everything (incl. last copy ops + tile31 stage)
  ITER_T(O1, VM0, 1);
  // tile 31 (buf1): compute only
  ITER_T(O1, ((void)0), 0);

#undef ITER_C
#undef ITER_T
#undef READ_ALL
#undef O0
#undef O1
#undef O2
#undef VM5
#undef VM3
#undef VM0
#undef MFMA_H
#undef LDFRAG
#undef STAGE

  // finish copy: chunks 30 (in cbuf) and 31
  cdst2[0] = cbuf;
  float2 clast = csrc2[512];
  cdst2[512] = clast;

  // ---- epilogue: per-row square-sum over this wave's 64 cols; 2 N-halves
  // reduce via LDS; ONE non-atomic store per row into this block's slot.
  __syncthreads();
  float* red = (float*)ldsA;    // [256 rows][2 wave-cols]
#pragma unroll
  for (int m = 0; m < 4; m++) {
#pragma unroll
    for (int r = 0; r < 4; r++) {
      float v = 0.f;
#pragma unroll
      for (int n = 0; n < 4; n++) { float x = acc[m][n][r]; v += x * x; }
      v += __shfl_xor(v, 1, 64);
      v += __shfl_xor(v, 2, 64);
      v += __shfl_xor(v, 4, 64);
      v += __shfl_xor(v, 8, 64);
      if (lr == 0) {
        int lrow = wm + m * 16 + lk * 4 + r;   // 0..255
        red[lrow * 2 + (w & 1)] = v;
      }
    }
  }
  __syncthreads();
  if (t < 256) {
    float s = red[t * 2 + 0] + red[t * 2 + 1];
    // slot: [row][cluster][half] — exactly one writer per slot, no atomic
    s_part[((size_t)(bm + t) * NCLUST + (bx >> 1)) * 2 + (bx & 1)] = s;
  }
}

// ---------------- softmax over 16 clusters per row (sums the 2 partials) ----------------
__global__ __launch_bounds__(256) void softmax_kernel(const float* __restrict__ s_part,
                                                      float* __restrict__ out0) {
  int r = blockIdx.x * 256 + threadIdx.x;
  const float4* sp = (const float4*)(s_part + (size_t)r * 32);
  float v[16];
#pragma unroll
  for (int i = 0; i < 8; i++) {
    float4 a = sp[i];
    v[i * 2 + 0] = a.x + a.y;
    v[i * 2 + 1] = a.z + a.w;
  }
  // logits = (s_scaled / 2^24) / TEMP ; eta*d cancels in softmax
  const float lsc = 5.9604644775390625e-7f;   // 10 / 2^24
  float mx = -1e30f;
#pragma unroll
  for (int i = 0; i < 16; i++) { v[i] *= lsc; mx = fmaxf(mx, v[i]); }
  float sum = 0.f;
#pragma unroll
  for (int i = 0; i < 16; i++) { v[i] = __expf(v[i] - mx); sum += v[i]; }
  float rs = 1.0f / sum;
  float4* op = (float4*)(out0 + (size_t)r * 16);
#pragma unroll
  for (int i = 0; i < 4; i++) {
    float4 a;
    a.x = v[i * 4 + 0] * rs; a.y = v[i * 4 + 1] * rs;
    a.z = v[i * 4 + 2] * rs; a.w = v[i * 4 + 3] * rs;
    op[i] = a;
  }
}

extern "C" void kernel_launch(void* const* d_in, const int* in_sizes, int n_in,
                              void* d_out, int out_size, void* d_ws, size_t ws_size,
                              hipStream_t stream) {
  const float* z = (const float*)d_in[0];
  const float* D = (const float*)d_in[1];
  float* out0 = (float*)d_out;
  float* out1 = out0 + (size_t)M_DIM * NCLUST;

  char* ws = (char*)d_ws;
  u8* zn   = (u8*)ws;                                                 // 32 MB
  u8* dnt  = (u8*)(ws + (size_t)M_DIM * KB4);                         // 8 MB
  float* colsq  = (float*)(ws + (size_t)M_DIM * KB4 + (size_t)N_DIM * KB4);
  float* s_part = colsq + N_DIM;                                      // [M][16][2] = 2 MB

  zero_kernel<<<(N_DIM + 255) / 256, 256, 0, stream>>>(colsq, N_DIM);
  znorm_kernel<<<M_DIM, 256, 0, stream>>>(z, zn);
  colsq_kernel<<<dim3(N_DIM / 256, N_DIM / 128), 256, 0, stream>>>(D, colsq);
  dnt_kernel<<<dim3(N_DIM / 64, N_DIM / 64), 256, 0, stream>>>(D, colsq, dnt);
  gemm_kernel<<<(M_DIM / BM) * (N_DIM / BN), 512, 0, stream>>>(zn, dnt, z, out1, s_part);
  softmax_kernel<<<M_DIM / 256, 256, 0, stream>>>(s_part, out0);
}

// Round 20
// 354.965 us; speedup vs baseline: 1.1816x; 1.1816x over previous
//
#include <hip/hip_runtime.h>

#define M_DIM 16384
#define N_DIM 4096
#define K_DIM 4096
#define NCLUST 16

#define BM 128
#define BN 128
#define KB4 2048              // bytes per row (fp4: 4096 elements / 2)
#define TKB 64                // K-tile bytes per row (128 fp4 elements)
#define NT 32                 // K-tiles

typedef unsigned short u16;
typedef unsigned char u8;
typedef float floatx4 __attribute__((ext_vector_type(4)));
typedef int int4v __attribute__((ext_vector_type(4)));
typedef int int8v __attribute__((ext_vector_type(8)));

typedef const unsigned int __attribute__((address_space(1))) gu32;
typedef unsigned int __attribute__((address_space(3))) lu32;

// float -> fp4 e2m1 code (values pre-scaled to ~N(0,1)); grid {0,.5,1,1.5,2,3,4,6}
__device__ __forceinline__ unsigned f2fp4(float x) {
  unsigned s = (__float_as_uint(x) >> 28) & 0x8u;
  float ax = fabsf(x);
  unsigned m;
  if      (ax < 0.25f) m = 0;
  else if (ax < 0.75f) m = 1;
  else if (ax < 1.25f) m = 2;
  else if (ax < 1.75f) m = 3;
  else if (ax < 2.5f)  m = 4;
  else if (ax < 3.5f)  m = 5;
  else if (ax < 5.0f)  m = 6;
  else                 m = 7;
  return s | m;
}

// ---------------- zero colsq only (s_part is fully written each call) ----------------
__global__ __launch_bounds__(256) void zero_kernel(float* __restrict__ p, int n) {
  int i = blockIdx.x * 256 + threadIdx.x;
  if (i < n) p[i] = 0.f;
}

// ---------------- z row-normalize -> fp4 (x64); out1 copy fused into GEMM ----------------
__global__ __launch_bounds__(256) void znorm_kernel(const float* __restrict__ z,
                                                    u8* __restrict__ zn) {
  const int row = blockIdx.x;
  const int t = threadIdx.x;
  const size_t base = (size_t)row * K_DIM;
  const float4* zr = (const float4*)(z + base);
  float4 v[4];                       // 16 contiguous elements: 16t .. 16t+15
  float ss = 0.f;
#pragma unroll
  for (int i = 0; i < 4; i++) {
    v[i] = zr[t * 4 + i];
    ss += v[i].x * v[i].x + v[i].y * v[i].y + v[i].z * v[i].z + v[i].w * v[i].w;
  }
#pragma unroll
  for (int m = 1; m <= 32; m <<= 1) ss += __shfl_xor(ss, m, 64);
  __shared__ float red[4];
  if ((t & 63) == 0) red[t >> 6] = ss;
  __syncthreads();
  float tot = red[0] + red[1] + red[2] + red[3];
  float sc = 64.0f / fmaxf(sqrtf(tot), 1e-8f);
  uint2* znr = (uint2*)(zn + (size_t)row * KB4);
  unsigned wlo = 0, whi = 0;
#pragma unroll
  for (int i = 0; i < 4; i++) {
    unsigned p = f2fp4(v[i].x * sc) | (f2fp4(v[i].y * sc) << 4) |
                 (f2fp4(v[i].z * sc) << 8) | (f2fp4(v[i].w * sc) << 12);
    if (i < 2) wlo |= p << (16 * i); else whi |= p << (16 * (i - 2));
  }
  uint2 pk; pk.x = wlo; pk.y = whi;
  znr[t] = pk;
}

// ---------------- D column squared-norms ----------------
__global__ __launch_bounds__(256) void colsq_kernel(const float* __restrict__ D,
                                                    float* __restrict__ colsq) {
  const int col = blockIdx.x * 256 + threadIdx.x;
  const int r0 = blockIdx.y * 128;
  float ss = 0.f;
#pragma unroll 4
  for (int r = 0; r < 128; r++) {
    float d = D[(size_t)(r0 + r) * N_DIM + col];
    ss += d * d;
  }
  atomicAdd(&colsq[col], ss);
}

// ---------------- D col-normalize + transpose -> fp4 (x64) DnT[N][K/2] ----------------
__global__ __launch_bounds__(256) void dnt_kernel(const float* __restrict__ D,
                                                  const float* __restrict__ colsq,
                                                  u8* __restrict__ dnt) {
  __shared__ float tile[64][65];
  const int c0 = blockIdx.x * 64, r0 = blockIdx.y * 64;
  const int t = threadIdx.x;
  const int tr = t >> 4;
  const int tc = (t & 15) * 4;
#pragma unroll
  for (int i = 0; i < 4; i++) {
    int row = i * 16 + tr;
    float4 v = *(const float4*)(D + (size_t)(r0 + row) * N_DIM + c0 + tc);
    tile[row][tc + 0] = v.x; tile[row][tc + 1] = v.y;
    tile[row][tc + 2] = v.z; tile[row][tc + 3] = v.w;
  }
  __syncthreads();
#pragma unroll
  for (int i = 0; i < 4; i++) {
    int nl = i * 16 + tr;
    float sc = 64.0f / fmaxf(sqrtf(colsq[c0 + nl]), 1e-8f);
    u16 pk = (u16)(f2fp4(tile[tc + 0][nl] * sc) | (f2fp4(tile[tc + 1][nl] * sc) << 4) |
                   (f2fp4(tile[tc + 2][nl] * sc) << 8) | (f2fp4(tile[tc + 3][nl] * sc) << 12));
    *(u16*)(dnt + (size_t)(c0 + nl) * KB4 + ((r0 + tc) >> 1)) = pk;
  }
}

// ---------------- GEMM: 128x128 tile, 4 waves, 3 blocks/CU, fp4 ----------------
// R20 = R18's per-wave math (64x64/wave, 0-conflict swizzle, full-def refills,
// refill-in-MFMA-shadow, depth-2 3-buffer pipeline, non-atomic s_part, tail
// copy) re-geometried to 128x128 tiles with 256-thread blocks so THREE blocks
// co-reside per CU (LDS 3x48=144<=160 KB; regs 3x136<=512/SIMD). Cross-block
// wave overlap fills the barrier/staging stalls that single-block scheduling
// could not hide (R11/R15/R16/R19 all failed to fix this in-block).
__global__ __launch_bounds__(256, 3) void gemm_kernel(const u8* __restrict__ zn,
                                                      const u8* __restrict__ dnt,
                                                      const float* __restrict__ zsrc,
                                                      float* __restrict__ out1,
                                                      float* __restrict__ s_part) {
  __shared__ u8 ldsA[3 * BM * TKB];   // 3 x 8 KB
  __shared__ u8 ldsB[3 * BN * TKB];   // 3 x 8 KB -> 48 KB total

  const int t = threadIdx.x;
  const int w = t >> 6, l = t & 63;
  const int lr = l & 15, lk = l >> 4;

  // XCD swizzle: 4096 blocks, 512 contiguous work-ids per XCD
  const int bid = blockIdx.x;
  const int swz = (bid & 7) * 512 + (bid >> 3);
  const int bx = swz & 31, by = swz >> 5;
  const int bm = by * BM, bn = bx * BN;
  const int wm = (w >> 1) * 64, wn = (w & 1) * 64;

  // ---- staging: pre-swizzled per-lane sources, wave-uniform LDS dests ----
  // 256 threads cover 64 rows x 4 slots per op; 2 ops each for A and B.
  const int sslot = (t & 3) ^ ((t >> 3) & 3);
  const u8* pA = zn + (size_t)(bm + (t >> 2)) * KB4 + sslot * 16;
  const u8* pB = dnt + (size_t)(bn + (t >> 2)) * KB4 + sslot * 16;

#define STAGE(OA, KT) do { \
    __builtin_amdgcn_global_load_lds((gu32*)(pA + (KT) * TKB), \
        (lu32*)&ldsA[(OA) + w * 1024], 16, 0, 0); \
    __builtin_amdgcn_global_load_lds((gu32*)(pA + (size_t)64 * KB4 + (KT) * TKB), \
        (lu32*)&ldsA[(OA) + 4096 + w * 1024], 16, 0, 0); \
    __builtin_amdgcn_global_load_lds((gu32*)(pB + (KT) * TKB), \
        (lu32*)&ldsB[(OA) + w * 1024], 16, 0, 0); \
    __builtin_amdgcn_global_load_lds((gu32*)(pB + (size_t)64 * KB4 + (KT) * TKB), \
        (lu32*)&ldsB[(OA) + 4096 + w * 1024], 16, 0, 0); \
  } while (0)

  // ---- ds_read fragment byte offsets: slot = lk ^ ((row>>1)&3) ----
  int aOff[4], bOff[4];
#pragma unroll
  for (int m = 0; m < 4; m++) {
    int row = wm + m * 16 + lr;
    aOff[m] = row * TKB + ((lk ^ ((row >> 1) & 3)) * 16);
  }
#pragma unroll
  for (int n = 0; n < 4; n++) {
    int row = wn + n * 16 + lr;
    bOff[n] = row * TKB + ((lk ^ ((row >> 1) & 3)) * 16);
  }

  int8v af[4], bf[4];
  floatx4 acc[4][4] = {};

  // full-def refill: low half from LDS, high half zeroed (fp4 reads v[0:3])
#define LDFRAG(F, base, off) do { \
    int4v* _h = (int4v*)&(F); \
    _h[0] = *(const int4v*)((base) + (off)); \
    _h[1] = (int4v){0, 0, 0, 0}; \
  } while (0)

  // full-tile preload (prologue only)
#define READ_ALL(OA) do { \
    const u8* _ab = ldsA + (OA); \
    const u8* _bb = ldsB + (OA); \
    _Pragma("unroll") \
    for (int ni = 0; ni < 4; ni++) LDFRAG(bf[ni], _bb, bOff[ni]); \
    _Pragma("unroll") \
    for (int mi = 0; mi < 4; mi++) LDFRAG(af[mi], _ab, aOff[mi]); \
  } while (0)

#define MFMA_H(M0) do { \
    __builtin_amdgcn_s_setprio(1); \
    _Pragma("unroll") \
    for (int mi = 0; mi < 2; mi++) \
      _Pragma("unroll") \
      for (int ni = 0; ni < 4; ni++) \
        acc[(M0) + mi][ni] = __builtin_amdgcn_mfma_scale_f32_16x16x128_f8f6f4( \
            af[(M0) + mi], bf[ni], acc[(M0) + mi][ni], 4, 4, 0, 127u, 0, 127u); \
    __builtin_amdgcn_s_setprio(0); \
  } while (0)

#define VM4 asm volatile("s_waitcnt vmcnt(4)" ::: "memory")
#define VM0 asm volatile("s_waitcnt vmcnt(0)" ::: "memory")

  // one pipelined K-tile: all 8 frags of tile kt preloaded. ON = next buf.
#define ITER(OC, ON, STG, WT, RDNEXT) do { \
    __builtin_amdgcn_s_barrier(); \
    __builtin_amdgcn_sched_barrier(0); \
    STG; \
    MFMA_H(0); \
    WT; \
    if (RDNEXT) { \
      LDFRAG(af[0], ldsA + (ON), aOff[0]); \
      LDFRAG(af[1], ldsA + (ON), aOff[1]); \
    } \
    MFMA_H(2); \
    if (RDNEXT) { \
      const u8* _bb = ldsB + (ON); \
      _Pragma("unroll") \
      for (int ni = 0; ni < 4; ni++) LDFRAG(bf[ni], _bb, bOff[ni]); \
      LDFRAG(af[2], ldsA + (ON), aOff[2]); \
      LDFRAG(af[3], ldsA + (ON), aOff[3]); \
    } \
  } while (0)

#define O0 0
#define O1 8192
#define O2 16384

  // prologue: stage tiles 0,1; drain tile0 (keep tile1 flying); preload frags
  STAGE(O0, 0); STAGE(O1, 1);
  VM4;
  __builtin_amdgcn_s_barrier();
  READ_ALL(O0);

  for (int kt = 0; kt < NT - 2; kt += 3) {
    ITER(O0, O1, STAGE(O2, kt + 2), VM4, 1);
    ITER(O1, O2, STAGE(O0, kt + 3), VM4, 1);
    ITER(O2, O0, STAGE(O1, kt + 4), VM4, 1);
  }
  // kt = NT-2 (buf0): no stage; land tile NT-1; refill its frags
  ITER(O0, O1, ((void)0), VM0, 1);
  // kt = NT-1 (buf1): compute only
  ITER(O1, O1, ((void)0), ((void)0), 0);

#undef ITER
#undef READ_ALL
#undef O0
#undef O1
#undef O2
#undef VM4
#undef VM0
#undef MFMA_H
#undef LDFRAG
#undef STAGE

  // ---- epilogue: per-row square-sum over this wave's 64 cols; 2 N-halves
  // reduce via LDS; ONE non-atomic store per row into this block's slot.
  __syncthreads();
  float* red = (float*)ldsA;    // [128 rows][2 wave-cols]
#pragma unroll
  for (int m = 0; m < 4; m++) {
#pragma unroll
    for (int r = 0; r < 4; r++) {
      float v = 0.f;
#pragma unroll
      for (int n = 0; n < 4; n++) { float x = acc[m][n][r]; v += x * x; }
      v += __shfl_xor(v, 1, 64);
      v += __shfl_xor(v, 2, 64);
      v += __shfl_xor(v, 4, 64);
      v += __shfl_xor(v, 8, 64);
      if (lr == 0) {
        int lrow = wm + m * 16 + lk * 4 + r;   // 0..127
        red[lrow * 2 + (w & 1)] = v;
      }
    }
  }
  __syncthreads();
  if (t < 128) {
    float s = red[t * 2 + 0] + red[t * 2 + 1];
    // slot: [row][cluster][half] — exactly one writer per slot, no atomic
    s_part[((size_t)(bm + t) * NCLUST + (bx >> 1)) * 2 + (bx & 1)] = s;
  }

  // ---- tail-fused copy: this block's 16384-float slice of z -> out1 ----
  {
    const float4* cs = (const float4*)zsrc + (size_t)bid * 4096 + t;
    float4* cd = (float4*)out1 + (size_t)bid * 4096 + t;
#pragma unroll
    for (int j = 0; j < 16; j += 4) {
      float4 a0 = cs[(j + 0) * 256];
      float4 a1 = cs[(j + 1) * 256];
      float4 a2 = cs[(j + 2) * 256];
      float4 a3 = cs[(j + 3) * 256];
      cd[(j + 0) * 256] = a0;
      cd[(j + 1) * 256] = a1;
      cd[(j + 2) * 256] = a2;
      cd[(j + 3) * 256] = a3;
    }
  }
}

// ---------------- softmax over 16 clusters per row (sums the 2 partials) ----------------
__global__ __launch_bounds__(256) void softmax_kernel(const float* __restrict__ s_part,
                                                      float* __restrict__ out0) {
  int r = blockIdx.x * 256 + threadIdx.x;
  const float4* sp = (const float4*)(s_part + (size_t)r * 32);
  float v[16];
#pragma unroll
  for (int i = 0; i < 8; i++) {
    float4 a = sp[i];
    v[i * 2 + 0] = a.x + a.y;
    v[i * 2 + 1] = a.z + a.w;
  }
  // logits = (s_scaled / 2^24) / TEMP ; eta*d cancels in softmax
  const float lsc = 5.9604644775390625e-7f;   // 10 / 2^24
  float mx = -1e30f;
#pragma unroll
  for (int i = 0; i < 16; i++) { v[i] *= lsc; mx = fmaxf(mx, v[i]); }
  float sum = 0.f;
#pragma unroll
  for (int i = 0; i < 16; i++) { v[i] = __expf(v[i] - mx); sum += v[i]; }
  float rs = 1.0f / sum;
  float4* op = (float4*)(out0 + (size_t)r * 16);
#pragma unroll
  for (int i = 0; i < 4; i++) {
    float4 a;
    a.x = v[i * 4 + 0] * rs; a.y = v[i * 4 + 1] * rs;
    a.z = v[i * 4 + 2] * rs; a.w = v[i * 4 + 3] * rs;
    op[i] = a;
  }
}

extern "C" void kernel_launch(void* const* d_in, const int* in_sizes, int n_in,
                              void* d_out, int out_size, void* d_ws, size_t ws_size,
                              hipStream_t stream) {
  const float* z = (const float*)d_in[0];
  const float* D = (const float*)d_in[1];
  float* out0 = (float*)d_out;
  float* out1 = out0 + (size_t)M_DIM * NCLUST;

  char* ws = (char*)d_ws;
  u8* zn   = (u8*)ws;                                                 // 32 MB
  u8* dnt  = (u8*)(ws + (size_t)M_DIM * KB4);                         // 8 MB
  float* colsq  = (float*)(ws + (size_t)M_DIM * KB4 + (size_t)N_DIM * KB4);
  float* s_part = colsq + N_DIM;                                      // [M][16][2] = 2 MB

  zero_kernel<<<(N_DIM + 255) / 256, 256, 0, stream>>>(colsq, N_DIM);
  znorm_kernel<<<M_DIM, 256, 0, stream>>>(z, zn);
  colsq_kernel<<<dim3(N_DIM / 256, N_DIM / 128), 256, 0, stream>>>(D, colsq);
  dnt_kernel<<<dim3(N_DIM / 64, N_DIM / 64), 256, 0, stream>>>(D, colsq, dnt);
  gemm_kernel<<<(M_DIM / BM) * (N_DIM / BN), 256, 0, stream>>>(zn, dnt, z, out1, s_part);
  softmax_kernel<<<M_DIM / 256, 256, 0, stream>>>(s_part, out0);
}

// Round 21
// 342.491 us; speedup vs baseline: 1.2246x; 1.0364x over previous
//
#include <hip/hip_runtime.h>

#define M_DIM 16384
#define N_DIM 4096
#define K_DIM 4096
#define NCLUST 16

#define BM 128
#define BN 128
#define KB4 2048              // bytes per row (fp4: 4096 elements / 2)
#define TKB 64                // K-tile bytes per row (128 fp4 elements)
#define NT 32                 // K-tiles

typedef unsigned short u16;
typedef unsigned char u8;
typedef float floatx4 __attribute__((ext_vector_type(4)));
typedef int int4v __attribute__((ext_vector_type(4)));
typedef int int8v __attribute__((ext_vector_type(8)));

typedef const unsigned int __attribute__((address_space(1))) gu32;
typedef unsigned int __attribute__((address_space(3))) lu32;

// float -> fp4 e2m1 code (values pre-scaled to ~N(0,1)); grid {0,.5,1,1.5,2,3,4,6}
__device__ __forceinline__ unsigned f2fp4(float x) {
  unsigned s = (__float_as_uint(x) >> 28) & 0x8u;
  float ax = fabsf(x);
  unsigned m;
  if      (ax < 0.25f) m = 0;
  else if (ax < 0.75f) m = 1;
  else if (ax < 1.25f) m = 2;
  else if (ax < 1.75f) m = 3;
  else if (ax < 2.5f)  m = 4;
  else if (ax < 3.5f)  m = 5;
  else if (ax < 5.0f)  m = 6;
  else                 m = 7;
  return s | m;
}

// ---------------- zero colsq only (s_part is fully written each call) ----------------
__global__ __launch_bounds__(256) void zero_kernel(float* __restrict__ p, int n) {
  int i = blockIdx.x * 256 + threadIdx.x;
  if (i < n) p[i] = 0.f;
}

// ---------------- z row-normalize -> fp4 (x64) + copy z -> out1 (shared read) ----------------
__global__ __launch_bounds__(256) void znorm_copy_kernel(const float* __restrict__ z,
                                                         float* __restrict__ out1,
                                                         u8* __restrict__ zn) {
  const int row = blockIdx.x;
  const int t = threadIdx.x;
  const size_t base = (size_t)row * K_DIM;
  const float4* zr = (const float4*)(z + base);
  float4 v[4];                       // 16 contiguous elements: 16t .. 16t+15
  float ss = 0.f;
#pragma unroll
  for (int i = 0; i < 4; i++) {
    v[i] = zr[t * 4 + i];
    ss += v[i].x * v[i].x + v[i].y * v[i].y + v[i].z * v[i].z + v[i].w * v[i].w;
  }
#pragma unroll
  for (int m = 1; m <= 32; m <<= 1) ss += __shfl_xor(ss, m, 64);
  __shared__ float red[4];
  if ((t & 63) == 0) red[t >> 6] = ss;
  __syncthreads();
  float tot = red[0] + red[1] + red[2] + red[3];
  float sc = 64.0f / fmaxf(sqrtf(tot), 1e-8f);
  float4* o1 = (float4*)(out1 + base);
  uint2* znr = (uint2*)(zn + (size_t)row * KB4);
  unsigned wlo = 0, whi = 0;
#pragma unroll
  for (int i = 0; i < 4; i++) {
    o1[t * 4 + i] = v[i];
    unsigned p = f2fp4(v[i].x * sc) | (f2fp4(v[i].y * sc) << 4) |
                 (f2fp4(v[i].z * sc) << 8) | (f2fp4(v[i].w * sc) << 12);
    if (i < 2) wlo |= p << (16 * i); else whi |= p << (16 * (i - 2));
  }
  uint2 pk; pk.x = wlo; pk.y = whi;
  znr[t] = pk;
}

// ---------------- D column squared-norms ----------------
__global__ __launch_bounds__(256) void colsq_kernel(const float* __restrict__ D,
                                                    float* __restrict__ colsq) {
  const int col = blockIdx.x * 256 + threadIdx.x;
  const int r0 = blockIdx.y * 128;
  float ss = 0.f;
#pragma unroll 4
  for (int r = 0; r < 128; r++) {
    float d = D[(size_t)(r0 + r) * N_DIM + col];
    ss += d * d;
  }
  atomicAdd(&colsq[col], ss);
}

// ---------------- D col-normalize + transpose -> fp4 (x64) DnT[N][K/2] ----------------
__global__ __launch_bounds__(256) void dnt_kernel(const float* __restrict__ D,
                                                  const float* __restrict__ colsq,
                                                  u8* __restrict__ dnt) {
  __shared__ float tile[64][65];
  const int c0 = blockIdx.x * 64, r0 = blockIdx.y * 64;
  const int t = threadIdx.x;
  const int tr = t >> 4;
  const int tc = (t & 15) * 4;
#pragma unroll
  for (int i = 0; i < 4; i++) {
    int row = i * 16 + tr;
    float4 v = *(const float4*)(D + (size_t)(r0 + row) * N_DIM + c0 + tc);
    tile[row][tc + 0] = v.x; tile[row][tc + 1] = v.y;
    tile[row][tc + 2] = v.z; tile[row][tc + 3] = v.w;
  }
  __syncthreads();
#pragma unroll
  for (int i = 0; i < 4; i++) {
    int nl = i * 16 + tr;
    float sc = 64.0f / fmaxf(sqrtf(colsq[c0 + nl]), 1e-8f);
    u16 pk = (u16)(f2fp4(tile[tc + 0][nl] * sc) | (f2fp4(tile[tc + 1][nl] * sc) << 4) |
                   (f2fp4(tile[tc + 2][nl] * sc) << 8) | (f2fp4(tile[tc + 3][nl] * sc) << 12));
    *(u16*)(dnt + (size_t)(c0 + nl) * KB4 + ((r0 + tc) >> 1)) = pk;
  }
}

// ---------------- GEMM: 128x128 tile, 4 waves, 3 blocks/CU, fp4 ----------------
// R21 = R20 WITHOUT the tail-fused copy (moved back to znorm_copy where the
// z read is shared). Rationale: R20's FETCH=507 MB showed the in-GEMM copy's
// 512 MB stream evicting zn/dnt from L3 (~210 MB of operand re-fetch). With
// a clean cache the K-loop's staging should be served from L2/L3.
__global__ __launch_bounds__(256, 3) void gemm_kernel(const u8* __restrict__ zn,
                                                      const u8* __restrict__ dnt,
                                                      float* __restrict__ s_part) {
  __shared__ u8 ldsA[3 * BM * TKB];   // 3 x 8 KB
  __shared__ u8 ldsB[3 * BN * TKB];   // 3 x 8 KB -> 48 KB total

  const int t = threadIdx.x;
  const int w = t >> 6, l = t & 63;
  const int lr = l & 15, lk = l >> 4;

  // XCD swizzle: 4096 blocks, 512 contiguous work-ids per XCD
  const int bid = blockIdx.x;
  const int swz = (bid & 7) * 512 + (bid >> 3);
  const int bx = swz & 31, by = swz >> 5;
  const int bm = by * BM, bn = bx * BN;
  const int wm = (w >> 1) * 64, wn = (w & 1) * 64;

  // ---- staging: pre-swizzled per-lane sources, wave-uniform LDS dests ----
  const int sslot = (t & 3) ^ ((t >> 3) & 3);
  const u8* pA = zn + (size_t)(bm + (t >> 2)) * KB4 + sslot * 16;
  const u8* pB = dnt + (size_t)(bn + (t >> 2)) * KB4 + sslot * 16;

#define STAGE(OA, KT) do { \
    __builtin_amdgcn_global_load_lds((gu32*)(pA + (KT) * TKB), \
        (lu32*)&ldsA[(OA) + w * 1024], 16, 0, 0); \
    __builtin_amdgcn_global_load_lds((gu32*)(pA + (size_t)64 * KB4 + (KT) * TKB), \
        (lu32*)&ldsA[(OA) + 4096 + w * 1024], 16, 0, 0); \
    __builtin_amdgcn_global_load_lds((gu32*)(pB + (KT) * TKB), \
        (lu32*)&ldsB[(OA) + w * 1024], 16, 0, 0); \
    __builtin_amdgcn_global_load_lds((gu32*)(pB + (size_t)64 * KB4 + (KT) * TKB), \
        (lu32*)&ldsB[(OA) + 4096 + w * 1024], 16, 0, 0); \
  } while (0)

  // ---- ds_read fragment byte offsets: slot = lk ^ ((row>>1)&3) ----
  int aOff[4], bOff[4];
#pragma unroll
  for (int m = 0; m < 4; m++) {
    int row = wm + m * 16 + lr;
    aOff[m] = row * TKB + ((lk ^ ((row >> 1) & 3)) * 16);
  }
#pragma unroll
  for (int n = 0; n < 4; n++) {
    int row = wn + n * 16 + lr;
    bOff[n] = row * TKB + ((lk ^ ((row >> 1) & 3)) * 16);
  }

  int8v af[4], bf[4];
  floatx4 acc[4][4] = {};

  // full-def refill: low half from LDS, high half zeroed (fp4 reads v[0:3])
#define LDFRAG(F, base, off) do { \
    int4v* _h = (int4v*)&(F); \
    _h[0] = *(const int4v*)((base) + (off)); \
    _h[1] = (int4v){0, 0, 0, 0}; \
  } while (0)

  // full-tile preload (prologue only)
#define READ_ALL(OA) do { \
    const u8* _ab = ldsA + (OA); \
    const u8* _bb = ldsB + (OA); \
    _Pragma("unroll") \
    for (int ni = 0; ni < 4; ni++) LDFRAG(bf[ni], _bb, bOff[ni]); \
    _Pragma("unroll") \
    for (int mi = 0; mi < 4; mi++) LDFRAG(af[mi], _ab, aOff[mi]); \
  } while (0)

#define MFMA_H(M0) do { \
    __builtin_amdgcn_s_setprio(1); \
    _Pragma("unroll") \
    for (int mi = 0; mi < 2; mi++) \
      _Pragma("unroll") \
      for (int ni = 0; ni < 4; ni++) \
        acc[(M0) + mi][ni] = __builtin_amdgcn_mfma_scale_f32_16x16x128_f8f6f4( \
            af[(M0) + mi], bf[ni], acc[(M0) + mi][ni], 4, 4, 0, 127u, 0, 127u); \
    __builtin_amdgcn_s_setprio(0); \
  } while (0)

#define VM4 asm volatile("s_waitcnt vmcnt(4)" ::: "memory")
#define VM0 asm volatile("s_waitcnt vmcnt(0)" ::: "memory")

  // one pipelined K-tile: all 8 frags of tile kt preloaded. ON = next buf.
#define ITER(OC, ON, STG, WT, RDNEXT) do { \
    __builtin_amdgcn_s_barrier(); \
    __builtin_amdgcn_sched_barrier(0); \
    STG; \
    MFMA_H(0); \
    WT; \
    if (RDNEXT) { \
      LDFRAG(af[0], ldsA + (ON), aOff[0]); \
      LDFRAG(af[1], ldsA + (ON), aOff[1]); \
    } \
    MFMA_H(2); \
    if (RDNEXT) { \
      const u8* _bb = ldsB + (ON); \
      _Pragma("unroll") \
      for (int ni = 0; ni < 4; ni++) LDFRAG(bf[ni], _bb, bOff[ni]); \
      LDFRAG(af[2], ldsA + (ON), aOff[2]); \
      LDFRAG(af[3], ldsA + (ON), aOff[3]); \
    } \
  } while (0)

#define O0 0
#define O1 8192
#define O2 16384

  // prologue: stage tiles 0,1; drain tile0 (keep tile1 flying); preload frags
  STAGE(O0, 0); STAGE(O1, 1);
  VM4;
  __builtin_amdgcn_s_barrier();
  READ_ALL(O0);

  for (int kt = 0; kt < NT - 2; kt += 3) {
    ITER(O0, O1, STAGE(O2, kt + 2), VM4, 1);
    ITER(O1, O2, STAGE(O0, kt + 3), VM4, 1);
    ITER(O2, O0, STAGE(O1, kt + 4), VM4, 1);
  }
  // kt = NT-2 (buf0): no stage; land tile NT-1; refill its frags
  ITER(O0, O1, ((void)0), VM0, 1);
  // kt = NT-1 (buf1): compute only
  ITER(O1, O1, ((void)0), ((void)0), 0);

#undef ITER
#undef READ_ALL
#undef O0
#undef O1
#undef O2
#undef VM4
#undef VM0
#undef MFMA_H
#undef LDFRAG
#undef STAGE

  // ---- epilogue: per-row square-sum over this wave's 64 cols; 2 N-halves
  // reduce via LDS; ONE non-atomic store per row into this block's slot.
  __syncthreads();
  float* red = (float*)ldsA;    // [128 rows][2 wave-cols]
#pragma unroll
  for (int m = 0; m < 4; m++) {
#pragma unroll
    for (int r = 0; r < 4; r++) {
      float v = 0.f;
#pragma unroll
      for (int n = 0; n < 4; n++) { float x = acc[m][n][r]; v += x * x; }
      v += __shfl_xor(v, 1, 64);
      v += __shfl_xor(v, 2, 64);
      v += __shfl_xor(v, 4, 64);
      v += __shfl_xor(v, 8, 64);
      if (lr == 0) {
        int lrow = wm + m * 16 + lk * 4 + r;   // 0..127
        red[lrow * 2 + (w & 1)] = v;
      }
    }
  }
  __syncthreads();
  if (t < 128) {
    float s = red[t * 2 + 0] + red[t * 2 + 1];
    // slot: [row][cluster][half] — exactly one writer per slot, no atomic
    s_part[((size_t)(bm + t) * NCLUST + (bx >> 1)) * 2 + (bx & 1)] = s;
  }
}

// ---------------- softmax over 16 clusters per row (sums the 2 partials) ----------------
__global__ __launch_bounds__(256) void softmax_kernel(const float* __restrict__ s_part,
                                                      float* __restrict__ out0) {
  int r = blockIdx.x * 256 + threadIdx.x;
  const float4* sp = (const float4*)(s_part + (size_t)r * 32);
  float v[16];
#pragma unroll
  for (int i = 0; i < 8; i++) {
    float4 a = sp[i];
    v[i * 2 + 0] = a.x + a.y;
    v[i * 2 + 1] = a.z + a.w;
  }
  // logits = (s_scaled / 2^24) / TEMP ; eta*d cancels in softmax
  const float lsc = 5.9604644775390625e-7f;   // 10 / 2^24
  float mx = -1e30f;
#pragma unroll
  for (int i = 0; i < 16; i++) { v[i] *= lsc; mx = fmaxf(mx, v[i]); }
  float sum = 0.f;
#pragma unroll
  for (int i = 0; i < 16; i++) { v[i] = __expf(v[i] - mx); sum += v[i]; }
  float rs = 1.0f / sum;
  float4* op = (float4*)(out0 + (size_t)r * 16);
#pragma unroll
  for (int i = 0; i < 4; i++) {
    float4 a;
    a.x = v[i * 4 + 0] * rs; a.y = v[i * 4 + 1] * rs;
    a.z = v[i * 4 + 2] * rs; a.w = v[i * 4 + 3] * rs;
    op[i] = a;
  }
}

extern "C" void kernel_launch(void* const* d_in, const int* in_sizes, int n_in,
                              void* d_out, int out_size, void* d_ws, size_t ws_size,
                              hipStream_t stream) {
  const float* z = (const float*)d_in[0];
  const float* D = (const float*)d_in[1];
  float* out0 = (float*)d_out;
  float* out1 = out0 + (size_t)M_DIM * NCLUST;

  char* ws = (char*)d_ws;
  u8* zn   = (u8*)ws;                                                 // 32 MB
  u8* dnt  = (u8*)(ws + (size_t)M_DIM * KB4);                         // 8 MB
  float* colsq  = (float*)(ws + (size_t)M_DIM * KB4 + (size_t)N_DIM * KB4);
  float* s_part = colsq + N_DIM;                                      // [M][16][2] = 2 MB

  zero_kernel<<<(N_DIM + 255) / 256, 256, 0, stream>>>(colsq, N_DIM);
  znorm_copy_kernel<<<M_DIM, 256, 0, stream>>>(z, out1, zn);
  colsq_kernel<<<dim3(N_DIM / 256, N_DIM / 128), 256, 0, stream>>>(D, colsq);
  dnt_kernel<<<dim3(N_DIM / 64, N_DIM / 64), 256, 0, stream>>>(D, colsq, dnt);
  gemm_kernel<<<(M_DIM / BM) * (N_DIM / BN), 256, 0, stream>>>(zn, dnt, s_part);
  softmax_kernel<<<M_DIM / 256, 256, 0, stream>>>(s_part, out0);
}